// Round 1
// baseline (566.523 us; speedup 1.0000x reference)
//
#include <hip/hip_runtime.h>
#include <hip/hip_bf16.h>

// LSTM cell: z = [x|h] @ Wstack^T + b ; gates -> c_t, h_t.
// M=4096, K=4096, N=2048 per gate x 4 gates. bf16 MFMA GEMM.
// R2: BK64, 16x16x32, 8-slot XOR swizzle (128B rows) -> 0 conflicts. KEEP.
// R4: 2x2 wave partition: 311us. R5: reg diet: flat. R6: BM=256 + XCD swizzle: 288us,
//     MfmaUtil 43, VALU 23, HBM 29% -> stall-bound 2-barrier structure (= its ~900TF ceiling).
// R7(this): 4-phase pipelined 256x256 tile (m201-style): 8 waves (2m x 4 h-quarters),
//     per-wave 128m x 16h x 4g (acc[4][8]=128 VGPR). B LDS h-quarter-major so each wave
//     reads only its own quarter but keeps all 4 gates (epilogue stays wave-local).
//     Staging for tile t+1 front-loaded into phases 0-1 of tile t (A then B), ~3 MFMA
//     phases of flight before the single __syncthreads() drain at tile boundary.
//     Raw s_barrier + setprio(1) around each 16-MFMA cluster.

#define M_DIM 4096
#define K_DIM 4096
#define H_DIM 2048
#define BK 64

// fallback (old, no-workspace path) config
#define BM 256
#define BH 32
#define NTHREADS 512

// pipelined config
#define BM2 256
#define BH2 64
#define NT2 512
#define KT (K_DIM / BK)

typedef __attribute__((ext_vector_type(8))) short bf16x8;
typedef __attribute__((ext_vector_type(8))) unsigned short u16x8;
typedef __attribute__((ext_vector_type(4))) float f32x4;

__device__ __forceinline__ unsigned short f2bf(float f) {
    union { float f; unsigned int u; } v; v.f = f;
    unsigned int u = v.u;
    unsigned int r = u + 0x7FFFu + ((u >> 16) & 1u);   // round-to-nearest-even
    return (unsigned short)(r >> 16);
}

__device__ __forceinline__ float sigmoid_f(float x) {
    return 1.0f / (1.0f + __expf(-x));
}
__device__ __forceinline__ float tanh_f(float x) {
    return 2.0f / (1.0f + __expf(-2.0f * x)) - 1.0f;
}

// [rows][64] shorts: 16B chunk c of row r stored at slot (c ^ (r&7)).
__device__ __forceinline__ int sw64(int row, int koff) {
    int c  = koff >> 3;
    int sc = c ^ (row & 7);
    return row * BK + sc * 8 + (koff & 7);
}

__device__ __forceinline__ void async_load16(const unsigned short* g, unsigned short* l) {
    __builtin_amdgcn_global_load_lds(
        (const __attribute__((address_space(1))) void*)g,
        (__attribute__((address_space(3))) void*)l,
        16, 0, 0);
}

// ---------------- fp32 -> bf16 conversion prepass ----------------
__global__ __launch_bounds__(256) void convert_all(
        const float* __restrict__ x, const float* __restrict__ h,
        const float* __restrict__ Wi, const float* __restrict__ Wf,
        const float* __restrict__ Wo, const float* __restrict__ Wc,
        u16x8* __restrict__ xh_bf, u16x8* __restrict__ w_bf) {
    const int XHT = (M_DIM * K_DIM) / 8;          // 2,097,152
    int t = blockIdx.x * 256 + threadIdx.x;       // 0 .. 6,291,455
    const float* src;
    u16x8* dst;
    if (t < XHT) {
        int e = t * 8;
        int row = e >> 12;
        int col = e & 4095;
        src = (col < 2048) ? &x[(size_t)row * 2048 + col]
                           : &h[(size_t)row * 2048 + (col - 2048)];
        dst = xh_bf + t;
    } else {
        int g2 = t - XHT;                         // 0 .. 4,194,303
        long e = (long)g2 * 8;
        int row = (int)(e >> 12);                 // 0..8191
        int col = (int)(e & 4095);
        int gate = row >> 11;
        const float* Ws = (gate == 0) ? Wi : (gate == 1) ? Wf : (gate == 2) ? Wo : Wc;
        src = &Ws[(size_t)(row & 2047) * 4096 + col];
        dst = w_bf + g2;
    }
    float4 v0 = *(const float4*)src;
    float4 v1 = *(const float4*)(src + 4);
    u16x8 o;
    o[0] = f2bf(v0.x); o[1] = f2bf(v0.y); o[2] = f2bf(v0.z); o[3] = f2bf(v0.w);
    o[4] = f2bf(v1.x); o[5] = f2bf(v1.y); o[6] = f2bf(v1.z); o[7] = f2bf(v1.w);
    *dst = o;
}

// ---------------- R7: 4-phase pipelined GEMM (workspace path) ----------------
// grid 512 (XCD-swizzled): xcd = bid&7 owns m-rows {2xcd, 2xcd+1}; 32 n-blocks each.
// Block: 512 thr = 8 waves (wm = w>>2 in {0,1}: 128 m-rows; wh = w&3: h-quarter of 16).
// B LDS layout: row' = q*64 + gate*16 + hrow  (q = h-quarter) -> wave wh reads rows
// [wh*64, wh*64+64) only, yet holds all 4 gates for the wave-local epilogue.
__global__ __launch_bounds__(NT2, 2) void lstm_gemm_pipe(
    const unsigned short* __restrict__ xh_bf, const unsigned short* __restrict__ w_bf,
    const float* __restrict__ b_i, const float* __restrict__ b_f,
    const float* __restrict__ b_o, const float* __restrict__ b_c,
    const float* __restrict__ c_prev,
    float* __restrict__ h_out, float* __restrict__ c_out) {

    __shared__ __align__(16) unsigned short sA2[2][BM2 * BK];      // 2 x 32KB
    __shared__ __align__(16) unsigned short sB2[2][4 * BH2 * BK];  // 2 x 32KB (256 rows x 64)

    const int tid  = threadIdx.x;
    const int w    = tid >> 6;
    const int lane = tid & 63;
    const int l16  = lane & 15;
    const int quad = lane >> 4;
    const int wm   = w >> 2;           // 0..1 : m-half (128 rows)
    const int wh   = w & 3;            // 0..3 : h-quarter (16 cols)
    const int s7   = l16 & 7;

    const int bid  = blockIdx.x;       // 0..511
    const int xcd  = bid & 7;
    const int slot = bid >> 3;         // 0..63
    const int mRow = xcd * 2 + (slot >> 5);   // 0..15
    const int nIdx = slot & 31;               // 0..31
    const int mBase = mRow * BM2;
    const int nBase = nIdx * BH2;

    f32x4 acc[4][8] = {};   // [gate][mt] : 128 regs

    // Staging addresses. Thread t handles linear LDS chunks {tid + 512r}, i.e. LDS
    // row r0+64r, slot tid&7; global k-chunk pre-swizzled: c = (tid&7)^(r0&7).
    const int r0  = tid >> 3;                       // 0..63
    const int c8  = ((tid & 7) ^ (r0 & 7)) << 3;    // swizzled chunk offset (shorts)
    const unsigned short* aS = xh_bf + (size_t)(mBase + r0) * K_DIM + c8;
    const int g0  = (r0 >> 4) & 3;
    const int hr0 = r0 & 15;
    const unsigned short* bS = w_bf + (size_t)(g0 * H_DIM + nBase + hr0) * K_DIM + c8;
    const int dstA = tid * 8;                       // shorts; +r*4096 per r

    // prologue: stage tile 0 into buf 0, full drain
#pragma unroll
    for (int r = 0; r < 4; ++r)
        async_load16(aS + (size_t)r * 64 * K_DIM, &sA2[0][dstA + r * 4096]);
#pragma unroll
    for (int r = 0; r < 4; ++r)
        async_load16(bS + (size_t)r * 16 * K_DIM, &sB2[0][dstA + r * 4096]);
    __syncthreads();

    const int aO0 = (wm * 128 + l16) * BK;   // + mt*16*BK + chunk
    const int bO0 = (wh * 64 + l16) * BK;    // + g*16*BK  + chunk
    const int co0 = (quad ^ s7) << 3;        // kk=0 stored-chunk offset
    const int co1 = ((4 + quad) ^ s7) << 3;  // kk=1

    for (int t = 0; t < KT; ++t) {
        const unsigned short* sAb = sA2[t & 1];
        const unsigned short* sBb = sB2[t & 1];
        unsigned short* dA = sA2[(t + 1) & 1];
        unsigned short* dB = sB2[(t + 1) & 1];
        const unsigned short* aN = aS + (size_t)(t + 1) * BK;
        const unsigned short* bN = bS + (size_t)(t + 1) * BK;
        const bool st = (t + 1 < KT);

        bf16x8 av[4], bv[4];

        // ---- phase 0: kk=0, mt 0-3 ; issue next-tile A stage ----
#pragma unroll
        for (int mt = 0; mt < 4; ++mt)
            av[mt] = *(const bf16x8*)&sAb[aO0 + co0 + mt * (16 * BK)];
#pragma unroll
        for (int g = 0; g < 4; ++g)
            bv[g] = *(const bf16x8*)&sBb[bO0 + co0 + g * (16 * BK)];
        if (st) {
#pragma unroll
            for (int r = 0; r < 4; ++r)
                async_load16(aN + (size_t)r * 64 * K_DIM, &dA[dstA + r * 4096]);
        }
        __builtin_amdgcn_s_barrier();
        __builtin_amdgcn_s_setprio(1);
#pragma unroll
        for (int g = 0; g < 4; ++g)
#pragma unroll
            for (int mt = 0; mt < 4; ++mt)
                acc[g][mt] = __builtin_amdgcn_mfma_f32_16x16x32_bf16(
                    av[mt], bv[g], acc[g][mt], 0, 0, 0);
        __builtin_amdgcn_s_setprio(0);
        __builtin_amdgcn_s_barrier();

        // ---- phase 1: kk=0, mt 4-7 ; issue next-tile B stage (bv reused) ----
#pragma unroll
        for (int mt = 0; mt < 4; ++mt)
            av[mt] = *(const bf16x8*)&sAb[aO0 + co0 + (mt + 4) * (16 * BK)];
        if (st) {
#pragma unroll
            for (int r = 0; r < 4; ++r)
                async_load16(bN + (size_t)r * 16 * K_DIM, &dB[dstA + r * 4096]);
        }
        __builtin_amdgcn_s_barrier();
        __builtin_amdgcn_s_setprio(1);
#pragma unroll
        for (int g = 0; g < 4; ++g)
#pragma unroll
            for (int mt = 0; mt < 4; ++mt)
                acc[g][mt + 4] = __builtin_amdgcn_mfma_f32_16x16x32_bf16(
                    av[mt], bv[g], acc[g][mt + 4], 0, 0, 0);
        __builtin_amdgcn_s_setprio(0);
        __builtin_amdgcn_s_barrier();

        // ---- phase 2: kk=1, mt 0-3 ----
#pragma unroll
        for (int mt = 0; mt < 4; ++mt)
            av[mt] = *(const bf16x8*)&sAb[aO0 + co1 + mt * (16 * BK)];
#pragma unroll
        for (int g = 0; g < 4; ++g)
            bv[g] = *(const bf16x8*)&sBb[bO0 + co1 + g * (16 * BK)];
        __builtin_amdgcn_s_barrier();
        __builtin_amdgcn_s_setprio(1);
#pragma unroll
        for (int g = 0; g < 4; ++g)
#pragma unroll
            for (int mt = 0; mt < 4; ++mt)
                acc[g][mt] = __builtin_amdgcn_mfma_f32_16x16x32_bf16(
                    av[mt], bv[g], acc[g][mt], 0, 0, 0);
        __builtin_amdgcn_s_setprio(0);
        __builtin_amdgcn_s_barrier();

        // ---- phase 3: kk=1, mt 4-7 ; tile-boundary drain ----
#pragma unroll
        for (int mt = 0; mt < 4; ++mt)
            av[mt] = *(const bf16x8*)&sAb[aO0 + co1 + (mt + 4) * (16 * BK)];
        __builtin_amdgcn_s_barrier();
        __builtin_amdgcn_s_setprio(1);
#pragma unroll
        for (int g = 0; g < 4; ++g)
#pragma unroll
            for (int mt = 0; mt < 4; ++mt)
                acc[g][mt + 4] = __builtin_amdgcn_mfma_f32_16x16x32_bf16(
                    av[mt], bv[g], acc[g][mt + 4], 0, 0, 0);
        __builtin_amdgcn_s_setprio(0);
        __syncthreads();   // vmcnt(0)+lgkmcnt(0)+barrier: stages landed, reads retired
    }

    // Epilogue: wave-local (all 4 gates in-wave). C/D: col=lane&15 -> n, row=quad*4+i.
    {
        const int n = nBase + wh * 16 + l16;
        const float bi = b_i[n], bff = b_f[n], bo = b_o[n], bc = b_c[n];
#pragma unroll
        for (int mt = 0; mt < 8; ++mt) {
#pragma unroll
            for (int i = 0; i < 4; ++i) {
                int m = mBase + wm * 128 + mt * 16 + quad * 4 + i;
                float zi = acc[0][mt][i] + bi;
                float zf = acc[1][mt][i] + bff;
                float zo = acc[2][mt][i] + bo;
                float zc = acc[3][mt][i] + bc;
                float ig = sigmoid_f(zi);
                float fg = sigmoid_f(zf);
                float og = sigmoid_f(zo);
                float ch = tanh_f(zc);
                size_t idx = (size_t)m * H_DIM + n;
                float c = fg * c_prev[idx] + ig * ch;
                c_out[idx] = c;
                h_out[idx] = og * tanh_f(c);
            }
        }
    }
}

// ---------------- fallback GEMM (no workspace): old 2-barrier kernel ----------------
template <bool DMA>
__global__ __launch_bounds__(NTHREADS, 2) void lstm_gemm(
    const unsigned short* __restrict__ xh_bf, const unsigned short* __restrict__ w_bf,
    const float* __restrict__ x_t, const float* __restrict__ h_t_1,
    const float* __restrict__ Wi, const float* __restrict__ Wf,
    const float* __restrict__ Wo, const float* __restrict__ Wc,
    const float* __restrict__ b_i, const float* __restrict__ b_f,
    const float* __restrict__ b_o, const float* __restrict__ b_c,
    const float* __restrict__ c_prev,
    float* __restrict__ h_out, float* __restrict__ c_out) {

    __shared__ __align__(16) unsigned short sA[BM * BK];      // [256][64] 32KB
    __shared__ __align__(16) unsigned short sB[4 * BH * BK];  // [4][32][64] 16KB

    const int tid  = threadIdx.x;
    const int w    = tid >> 6;
    const int lane = tid & 63;
    const int l16  = lane & 15;
    const int quad = lane >> 4;
    const int wm   = w & 3;
    const int wh   = w >> 2;
    const int s7   = l16 & 7;

    const int bid  = blockIdx.x;
    const int xcd  = bid & 7;
    const int slot = bid >> 3;
    const int yIdx = xcd * 2 + (slot >> 6);
    const int nIdx = slot & 63;

    const int mBase = yIdx * BM;
    const int nBase = nIdx * BH;

    f32x4 acc[4][4] = {};

    const int aBase = (wm * 64 + l16) * BK;
    const int bBase = (wh * 16 + l16) * BK;

    const unsigned short* aSrc = nullptr;
    const unsigned short* bSrc = nullptr;
    if constexpr (DMA) {
        int arowi = tid >> 3;
        int alc   = (tid & 7) ^ (arowi & 7);
        aSrc = xh_bf + (size_t)(mBase + arowi) * K_DIM + alc * 8;
        int browi = (tid >> 3) & 31;
        int gate0 = tid >> 8;
        int blc   = (tid & 7) ^ (browi & 7);
        bSrc = w_bf + (size_t)(gate0 * H_DIM + nBase + browi) * K_DIM + blc * 8;
    }
    const int dmaDst = tid * 8;

    for (int k0 = 0; k0 < K_DIM; k0 += BK) {
        __syncthreads();
        if constexpr (DMA) {
#pragma unroll
            for (int r = 0; r < 4; ++r)
                async_load16(aSrc + (size_t)r * 64 * K_DIM, &sA[dmaDst + r * 4096]);
#pragma unroll
            for (int r = 0; r < 2; ++r)
                async_load16(bSrc + (size_t)r * 2 * H_DIM * K_DIM, &sB[dmaDst + r * 4096]);
            aSrc += BK;
            bSrc += BK;
        } else {
            const float* Asrc = (k0 < 2048) ? x_t : h_t_1;
            int kloc = k0 & 2047;
#pragma unroll
            for (int r = 0; r < 8; ++r) {
                int cc  = r * NTHREADS + tid;
                int row = cc >> 4;
                int ko  = (cc & 15) * 4;
                float4 v = *(const float4*)&Asrc[(size_t)(mBase + row) * 2048 + kloc + ko];
                *(ushort4*)&sA[sw64(row, ko)] =
                    make_ushort4(f2bf(v.x), f2bf(v.y), f2bf(v.z), f2bf(v.w));
            }
            const float* Wg[4] = {Wi, Wf, Wo, Wc};
#pragma unroll
            for (int r = 0; r < 4; ++r) {
                int cc   = r * NTHREADS + tid;
                int gate = cc >> 9;
                int row  = (cc >> 4) & 31;
                int ko   = (cc & 15) * 4;
                float4 v = *(const float4*)&Wg[gate][(size_t)(nBase + row) * K_DIM + k0 + ko];
                *(ushort4*)&sB[gate * (BH * BK) + sw64(row, ko)] =
                    make_ushort4(f2bf(v.x), f2bf(v.y), f2bf(v.z), f2bf(v.w));
            }
        }
        __syncthreads();

#pragma unroll
        for (int hk = 0; hk < 2; ++hk) {
            const int co = ((hk * 4 + quad) ^ s7) << 3;
            bf16x8 av[4];
#pragma unroll
            for (int mt = 0; mt < 4; ++mt)
                av[mt] = *(const bf16x8*)&sA[aBase + mt * (16 * BK) + co];
            bf16x8 bv[4];
#pragma unroll
            for (int g = 0; g < 4; ++g)
                bv[g] = *(const bf16x8*)&sB[g * (BH * BK) + bBase + co];
#pragma unroll
            for (int g = 0; g < 4; ++g)
#pragma unroll
                for (int mt = 0; mt < 4; ++mt)
                    acc[g][mt] = __builtin_amdgcn_mfma_f32_16x16x32_bf16(
                        av[mt], bv[g], acc[g][mt], 0, 0, 0);
        }
    }

    {
        int n = nBase + wh * 16 + l16;
        float bi = b_i[n], bf = b_f[n], bo = b_o[n], bc = b_c[n];
#pragma unroll
        for (int mt = 0; mt < 4; ++mt) {
#pragma unroll
            for (int i = 0; i < 4; ++i) {
                int m = mBase + wm * 64 + mt * 16 + quad * 4 + i;
                float zi = acc[0][mt][i] + bi;
                float zf = acc[1][mt][i] + bf;
                float zo = acc[2][mt][i] + bo;
                float zc = acc[3][mt][i] + bc;
                float ig = sigmoid_f(zi);
                float fg = sigmoid_f(zf);
                float og = sigmoid_f(zo);
                float ch = tanh_f(zc);
                size_t idx = (size_t)m * H_DIM + n;
                float c = fg * c_prev[idx] + ig * ch;
                c_out[idx] = c;
                h_out[idx] = og * tanh_f(c);
            }
        }
    }
}

extern "C" void kernel_launch(void* const* d_in, const int* in_sizes, int n_in,
                              void* d_out, int out_size, void* d_ws, size_t ws_size,
                              hipStream_t stream) {
    const float* x_t   = (const float*)d_in[0];
    const float* h_t_1 = (const float*)d_in[1];
    const float* c_t_1 = (const float*)d_in[2];
    const float* W_i   = (const float*)d_in[3];
    const float* b_i   = (const float*)d_in[4];
    const float* W_f   = (const float*)d_in[5];
    const float* b_f   = (const float*)d_in[6];
    const float* W_o   = (const float*)d_in[7];
    const float* b_o   = (const float*)d_in[8];
    const float* W_c   = (const float*)d_in[9];
    const float* b_c   = (const float*)d_in[10];

    float* h_out = (float*)d_out;
    float* c_out = h_out + (size_t)M_DIM * H_DIM;

    const size_t need = (size_t)M_DIM * K_DIM * 2 + (size_t)4 * H_DIM * K_DIM * 2; // 96 MB
    if (ws_size >= need) {
        unsigned short* xh_bf = (unsigned short*)d_ws;
        unsigned short* w_bf  = xh_bf + (size_t)M_DIM * K_DIM;
        int total_threads = (M_DIM * K_DIM + 4 * H_DIM * K_DIM) / 8;  // 6,291,456
        convert_all<<<total_threads / 256, 256, 0, stream>>>(
            x_t, h_t_1, W_i, W_f, W_o, W_c, (u16x8*)xh_bf, (u16x8*)w_bf);
        dim3 grid((H_DIM / BH2) * (M_DIM / BM2));   // 32 * 16 = 512, XCD-swizzled in-kernel
        lstm_gemm_pipe<<<grid, NT2, 0, stream>>>(
            xh_bf, w_bf, b_i, b_f, b_o, b_c, c_t_1, h_out, c_out);
    } else {
        dim3 grid((H_DIM / BH) * (M_DIM / BM));     // 1024
        lstm_gemm<false><<<grid, NTHREADS, 0, stream>>>(
            nullptr, nullptr, x_t, h_t_1, W_i, W_f, W_o, W_c,
            b_i, b_f, b_o, b_c, c_t_1, h_out, c_out);
    }
}

// Round 2
// 565.647 us; speedup vs baseline: 1.0015x; 1.0015x over previous
//
#include <hip/hip_runtime.h>
#include <hip/hip_bf16.h>

// LSTM cell: z = [x|h] @ Wstack^T + b ; gates -> c_t, h_t.
// M=4096, K=4096, N=2048 per gate x 4 gates. bf16 MFMA GEMM.
// R6: 2-barrier 256x32-tile, 3 blk/CU: 288us, MfmaUtil 43 (TLP-masked stalls).
// R7: 4-phase dbuf + __syncthreads drain: 337us REGRESSION. 1 blk/CU killed TLP and
//     the tile-boundary drain is vmcnt(0) on loads issued ~2 phases earlier.
// R8(this): counted-vmcnt deep pipeline (m201 mechanism): BK=32, ring-4 LDS
//     (4 x (16KB A + 16KB B) = 128KB), stage tile t+3 during tile t (A in phase 0,
//     B in phase 1), tile boundary = s_waitcnt vmcnt(8) + s_barrier -> forces only
//     tile t+1's loads (4-5 phases of flight), keeps 8 newest in flight. NEVER
//     vmcnt(0) in the main loop; tail peels vmcnt(4)/vmcnt(0). 2 phases/tile x
//     16 MFMA, setprio around clusters. Swizzle for 64B rows: slot = quad^((l16>>1)&3).

#define M_DIM 4096
#define K_DIM 4096
#define H_DIM 2048

// fallback (no-workspace path) config
#define BM 256
#define BH 32
#define BK 64
#define NTHREADS 512

// pipelined config
#define BM2 256
#define BH2 64
#define BKP 32
#define NT2 512
#define KT2 (K_DIM / BKP)          // 128
#define TILE_SH (BM2 * BKP)        // 8192 shorts = 16KB per ring slot per operand

typedef __attribute__((ext_vector_type(8))) short bf16x8;
typedef __attribute__((ext_vector_type(8))) unsigned short u16x8;
typedef __attribute__((ext_vector_type(4))) float f32x4;

__device__ __forceinline__ unsigned short f2bf(float f) {
    union { float f; unsigned int u; } v; v.f = f;
    unsigned int u = v.u;
    unsigned int r = u + 0x7FFFu + ((u >> 16) & 1u);   // round-to-nearest-even
    return (unsigned short)(r >> 16);
}

__device__ __forceinline__ float sigmoid_f(float x) {
    return 1.0f / (1.0f + __expf(-x));
}
__device__ __forceinline__ float tanh_f(float x) {
    return 2.0f / (1.0f + __expf(-2.0f * x)) - 1.0f;
}

// fallback swizzle: [rows][64] shorts, chunk c of row r at slot (c ^ (r&7)).
__device__ __forceinline__ int sw64(int row, int koff) {
    int c  = koff >> 3;
    int sc = c ^ (row & 7);
    return row * BK + sc * 8 + (koff & 7);
}

__device__ __forceinline__ void async_load16(const unsigned short* g, unsigned short* l) {
    __builtin_amdgcn_global_load_lds(
        (const __attribute__((address_space(1))) void*)g,
        (__attribute__((address_space(3))) void*)l,
        16, 0, 0);
}

// ---------------- fp32 -> bf16 conversion prepass ----------------
__global__ __launch_bounds__(256) void convert_all(
        const float* __restrict__ x, const float* __restrict__ h,
        const float* __restrict__ Wi, const float* __restrict__ Wf,
        const float* __restrict__ Wo, const float* __restrict__ Wc,
        u16x8* __restrict__ xh_bf, u16x8* __restrict__ w_bf) {
    const int XHT = (M_DIM * K_DIM) / 8;          // 2,097,152
    int t = blockIdx.x * 256 + threadIdx.x;       // 0 .. 6,291,455
    const float* src;
    u16x8* dst;
    if (t < XHT) {
        int e = t * 8;
        int row = e >> 12;
        int col = e & 4095;
        src = (col < 2048) ? &x[(size_t)row * 2048 + col]
                           : &h[(size_t)row * 2048 + (col - 2048)];
        dst = xh_bf + t;
    } else {
        int g2 = t - XHT;                         // 0 .. 4,194,303
        long e = (long)g2 * 8;
        int row = (int)(e >> 12);                 // 0..8191
        int col = (int)(e & 4095);
        int gate = row >> 11;
        const float* Ws = (gate == 0) ? Wi : (gate == 1) ? Wf : (gate == 2) ? Wo : Wc;
        src = &Ws[(size_t)(row & 2047) * 4096 + col];
        dst = w_bf + g2;
    }
    float4 v0 = *(const float4*)src;
    float4 v1 = *(const float4*)(src + 4);
    u16x8 o;
    o[0] = f2bf(v0.x); o[1] = f2bf(v0.y); o[2] = f2bf(v0.z); o[3] = f2bf(v0.w);
    o[4] = f2bf(v1.x); o[5] = f2bf(v1.y); o[6] = f2bf(v1.z); o[7] = f2bf(v1.w);
    *dst = o;
}

// ---------------- R8: counted-vmcnt ring-4 pipelined GEMM ----------------
// grid 512 (XCD-swizzled). 512 thr = 8 waves (wm = w>>2: 128 m-rows; wh = w&3:
// h-quarter). B LDS row' = q*64 + gate*16 + hrow -> wave wh reads only its quarter
// but holds all 4 gates (wave-local epilogue).
// Ring slots: tile t lives in slot t&3. During tile t stage tile t+3.
// Tile = 2 phases: {ds_read, stage-issue, barrier, 16 MFMA, barrier}.
// Boundary wait: vmcnt(8) (+barrier) -> tile t+1's 4 stage-instrs forced complete,
// tiles t+2/t+3 (8 instrs) stay in flight.

#define TILE_STEP(T, DO_STG, WAIT_OP) do {                                        \
    const int cur_ = (T) & 3;                                                     \
    const unsigned short* sAc = &sA[cur_ * TILE_SH];                              \
    const unsigned short* sBc = &sB[cur_ * TILE_SH];                              \
    /* ---- phase 0: mt 0-3 x g 0-3 ; stage A(T+3) ---- */                        \
    bf16x8 av0_[4], bv_[4];                                                       \
    _Pragma("unroll")                                                             \
    for (int mt = 0; mt < 4; ++mt)                                                \
        av0_[mt] = *(const bf16x8*)&sAc[aOff + mt * (16 * BKP)];                  \
    _Pragma("unroll")                                                             \
    for (int g = 0; g < 4; ++g)                                                   \
        bv_[g] = *(const bf16x8*)&sBc[bOff + g * (16 * BKP)];                     \
    if (DO_STG) {                                                                 \
        unsigned short* dA = &sA[(((T) + 3) & 3) * TILE_SH];                      \
        const unsigned short* s0 = aS + (size_t)((T) + 3) * BKP;                  \
        async_load16(s0, &dA[dstOff]);                                            \
        async_load16(s0 + (size_t)128 * K_DIM, &dA[dstOff + 4096]);               \
    }                                                                             \
    __builtin_amdgcn_s_barrier();                                                 \
    __builtin_amdgcn_s_setprio(1);                                                \
    _Pragma("unroll")                                                             \
    for (int g = 0; g < 4; ++g)                                                   \
        _Pragma("unroll")                                                         \
        for (int mt = 0; mt < 4; ++mt)                                            \
            acc[g][mt] = __builtin_amdgcn_mfma_f32_16x16x32_bf16(                 \
                av0_[mt], bv_[g], acc[g][mt], 0, 0, 0);                           \
    __builtin_amdgcn_s_setprio(0);                                                \
    __builtin_amdgcn_s_barrier();                                                 \
    /* ---- phase 1: mt 4-7 x g 0-3 (bv reused) ; stage B(T+3) ---- */            \
    bf16x8 av1_[4];                                                               \
    _Pragma("unroll")                                                             \
    for (int mt = 0; mt < 4; ++mt)                                                \
        av1_[mt] = *(const bf16x8*)&sAc[aOff + (mt + 4) * (16 * BKP)];            \
    if (DO_STG) {                                                                 \
        unsigned short* dB = &sB[(((T) + 3) & 3) * TILE_SH];                      \
        const unsigned short* s1 = bS + (size_t)((T) + 3) * BKP;                  \
        async_load16(s1, &dB[dstOff]);                                            \
        async_load16(s1 + (size_t)32 * K_DIM, &dB[dstOff + 4096]);                \
    }                                                                             \
    __builtin_amdgcn_s_barrier();                                                 \
    __builtin_amdgcn_s_setprio(1);                                                \
    _Pragma("unroll")                                                             \
    for (int g = 0; g < 4; ++g)                                                   \
        _Pragma("unroll")                                                         \
        for (int mt = 0; mt < 4; ++mt)                                            \
            acc[g][mt + 4] = __builtin_amdgcn_mfma_f32_16x16x32_bf16(             \
                av1_[mt], bv_[g], acc[g][mt + 4], 0, 0, 0);                       \
    __builtin_amdgcn_s_setprio(0);                                                \
    WAIT_OP;                                                                      \
    __builtin_amdgcn_s_barrier();                                                 \
} while (0)

__global__ __launch_bounds__(NT2, 2) void lstm_gemm_pipe(
    const unsigned short* __restrict__ xh_bf, const unsigned short* __restrict__ w_bf,
    const float* __restrict__ b_i, const float* __restrict__ b_f,
    const float* __restrict__ b_o, const float* __restrict__ b_c,
    const float* __restrict__ c_prev,
    float* __restrict__ h_out, float* __restrict__ c_out) {

    __shared__ __align__(16) unsigned short sA[4 * TILE_SH];   // 64KB ring
    __shared__ __align__(16) unsigned short sB[4 * TILE_SH];   // 64KB ring

    const int tid  = threadIdx.x;
    const int w    = tid >> 6;
    const int lane = tid & 63;
    const int l16  = lane & 15;
    const int quad = lane >> 4;
    const int wm   = w >> 2;           // 0..1 : m-half (128 rows)
    const int wh   = w & 3;            // 0..3 : h-quarter (16 cols/gate)

    const int bid  = blockIdx.x;       // 0..511
    const int xcd  = bid & 7;
    const int slot = bid >> 3;         // 0..63
    const int mRow = xcd * 2 + (slot >> 5);   // 0..15
    const int nIdx = slot & 31;               // 0..31
    const int mBase = mRow * BM2;
    const int nBase = nIdx * BH2;

    f32x4 acc[4][8] = {};   // [gate][mt] : 128 regs

    // ---- staging addresses (thread handles 2 chunks per operand per tile) ----
    // LDS linear chunk lc = tid + 512r: row = lc>>2 (= tid>>2 + 128r), slot = tid&3.
    // Stored global chunk c = slot ^ ((row>>1)&3) = (tid&3) ^ ((tid>>3)&3): const/thread.
    const int c8a  = (((tid & 3) ^ ((tid >> 3) & 3)) << 3);     // shorts
    const int row0 = tid >> 2;                                  // 0..127
    const unsigned short* aS = xh_bf + (size_t)(mBase + row0) * K_DIM + c8a;
    const int q0   = row0 >> 6;                                 // 0..1
    const int gat0 = (row0 >> 4) & 3;
    const int hr0  = row0 & 15;
    const unsigned short* bS =
        w_bf + (size_t)(gat0 * H_DIM + nBase + q0 * 16 + hr0) * K_DIM + c8a;
    const int dstOff = tid * 8;                                 // shorts; +4096 for r=1

    // ---- ds_read offsets ----
    // A row = wm*128 + mt*16 + l16; slot = quad ^ ((l16>>1)&3)  (<=2-way banks, free)
    const int slotSh = ((quad ^ ((l16 >> 1) & 3)) << 3);
    const int aOff = (wm * 128 + l16) * BKP + slotSh;           // + mt*16*BKP
    const int bOff = (wh * 64 + l16) * BKP + slotSh;            // + g*16*BKP

    // ---- prologue: stage tiles 0,1,2 (12 loads), force tile 0 (oldest 4) ----
#pragma unroll
    for (int p = 0; p < 3; ++p) {
        const unsigned short* a0 = aS + (size_t)p * BKP;
        const unsigned short* b0 = bS + (size_t)p * BKP;
        unsigned short* dA = &sA[p * TILE_SH];
        unsigned short* dB = &sB[p * TILE_SH];
        async_load16(a0, &dA[dstOff]);
        async_load16(a0 + (size_t)128 * K_DIM, &dA[dstOff + 4096]);
        async_load16(b0, &dB[dstOff]);
        async_load16(b0 + (size_t)32 * K_DIM, &dB[dstOff + 4096]);
    }
    asm volatile("s_waitcnt vmcnt(8)" ::: "memory");
    __builtin_amdgcn_s_barrier();

    // ---- main loop: tiles 0 .. KT2-4, staging ON, boundary vmcnt(8) ----
#pragma unroll 1
    for (int t = 0; t < KT2 - 3; ++t) {
        TILE_STEP(t, true, asm volatile("s_waitcnt vmcnt(8)" ::: "memory"));
    }
    // ---- tail: no staging; vmcnt(4) then vmcnt(0) then free-run ----
    TILE_STEP(KT2 - 3, false, asm volatile("s_waitcnt vmcnt(4)" ::: "memory"));
    TILE_STEP(KT2 - 2, false, asm volatile("s_waitcnt vmcnt(0)" ::: "memory"));
    TILE_STEP(KT2 - 1, false, (void)0);

    // ---- epilogue: wave-local. C/D: col=lane&15 -> n, row=quad*4+i ----
    {
        const int n = nBase + wh * 16 + l16;
        const float bi = b_i[n], bff = b_f[n], bo = b_o[n], bc = b_c[n];
#pragma unroll
        for (int mt = 0; mt < 8; ++mt) {
#pragma unroll
            for (int i = 0; i < 4; ++i) {
                int m = mBase + wm * 128 + mt * 16 + quad * 4 + i;
                float zi = acc[0][mt][i] + bi;
                float zf = acc[1][mt][i] + bff;
                float zo = acc[2][mt][i] + bo;
                float zc = acc[3][mt][i] + bc;
                float ig = sigmoid_f(zi);
                float fg = sigmoid_f(zf);
                float og = sigmoid_f(zo);
                float ch = tanh_f(zc);
                size_t idx = (size_t)m * H_DIM + n;
                float c = fg * c_prev[idx] + ig * ch;
                c_out[idx] = c;
                h_out[idx] = og * tanh_f(c);
            }
        }
    }
}

// ---------------- fallback GEMM (no workspace): R6 2-barrier kernel ----------------
__global__ __launch_bounds__(NTHREADS, 2) void lstm_gemm_fb(
    const float* __restrict__ x_t, const float* __restrict__ h_t_1,
    const float* __restrict__ Wi, const float* __restrict__ Wf,
    const float* __restrict__ Wo, const float* __restrict__ Wc,
    const float* __restrict__ b_i, const float* __restrict__ b_f,
    const float* __restrict__ b_o, const float* __restrict__ b_c,
    const float* __restrict__ c_prev,
    float* __restrict__ h_out, float* __restrict__ c_out) {

    __shared__ __align__(16) unsigned short sA[BM * BK];      // [256][64] 32KB
    __shared__ __align__(16) unsigned short sB[4 * BH * BK];  // [4][32][64] 16KB

    const int tid  = threadIdx.x;
    const int w    = tid >> 6;
    const int lane = tid & 63;
    const int l16  = lane & 15;
    const int quad = lane >> 4;
    const int wm   = w & 3;
    const int wh   = w >> 2;
    const int s7   = l16 & 7;

    const int bid  = blockIdx.x;
    const int xcd  = bid & 7;
    const int slot = bid >> 3;
    const int yIdx = xcd * 2 + (slot >> 6);
    const int nIdx = slot & 63;

    const int mBase = yIdx * BM;
    const int nBase = nIdx * BH;

    f32x4 acc[4][4] = {};

    const int aBase = (wm * 64 + l16) * BK;
    const int bBase = (wh * 16 + l16) * BK;

    for (int k0 = 0; k0 < K_DIM; k0 += BK) {
        __syncthreads();
        const float* Asrc = (k0 < 2048) ? x_t : h_t_1;
        int kloc = k0 & 2047;
#pragma unroll
        for (int r = 0; r < 8; ++r) {
            int cc  = r * NTHREADS + tid;
            int row = cc >> 4;
            int ko  = (cc & 15) * 4;
            float4 v = *(const float4*)&Asrc[(size_t)(mBase + row) * 2048 + kloc + ko];
            *(ushort4*)&sA[sw64(row, ko)] =
                make_ushort4(f2bf(v.x), f2bf(v.y), f2bf(v.z), f2bf(v.w));
        }
        const float* Wg[4] = {Wi, Wf, Wo, Wc};
#pragma unroll
        for (int r = 0; r < 4; ++r) {
            int cc   = r * NTHREADS + tid;
            int gate = cc >> 9;
            int row  = (cc >> 4) & 31;
            int ko   = (cc & 15) * 4;
            float4 v = *(const float4*)&Wg[gate][(size_t)(nBase + row) * K_DIM + k0 + ko];
            *(ushort4*)&sB[gate * (BH * BK) + sw64(row, ko)] =
                make_ushort4(f2bf(v.x), f2bf(v.y), f2bf(v.z), f2bf(v.w));
        }
        __syncthreads();

#pragma unroll
        for (int hk = 0; hk < 2; ++hk) {
            const int co = ((hk * 4 + quad) ^ s7) << 3;
            bf16x8 av[4];
#pragma unroll
            for (int mt = 0; mt < 4; ++mt)
                av[mt] = *(const bf16x8*)&sA[aBase + mt * (16 * BK) + co];
            bf16x8 bv[4];
#pragma unroll
            for (int g = 0; g < 4; ++g)
                bv[g] = *(const bf16x8*)&sB[g * (BH * BK) + bBase + co];
#pragma unroll
            for (int g = 0; g < 4; ++g)
#pragma unroll
                for (int mt = 0; mt < 4; ++mt)
                    acc[g][mt] = __builtin_amdgcn_mfma_f32_16x16x32_bf16(
                        av[mt], bv[g], acc[g][mt], 0, 0, 0);
        }
    }

    {
        int n = nBase + wh * 16 + l16;
        float bi = b_i[n], bf = b_f[n], bo = b_o[n], bc = b_c[n];
#pragma unroll
        for (int mt = 0; mt < 4; ++mt) {
#pragma unroll
            for (int i = 0; i < 4; ++i) {
                int m = mBase + wm * 64 + mt * 16 + quad * 4 + i;
                float zi = acc[0][mt][i] + bi;
                float zf = acc[1][mt][i] + bf;
                float zo = acc[2][mt][i] + bo;
                float zc = acc[3][mt][i] + bc;
                float ig = sigmoid_f(zi);
                float fg = sigmoid_f(zf);
                float og = sigmoid_f(zo);
                float ch = tanh_f(zc);
                size_t idx = (size_t)m * H_DIM + n;
                float c = fg * c_prev[idx] + ig * ch;
                c_out[idx] = c;
                h_out[idx] = og * tanh_f(c);
            }
        }
    }
}

extern "C" void kernel_launch(void* const* d_in, const int* in_sizes, int n_in,
                              void* d_out, int out_size, void* d_ws, size_t ws_size,
                              hipStream_t stream) {
    const float* x_t   = (const float*)d_in[0];
    const float* h_t_1 = (const float*)d_in[1];
    const float* c_t_1 = (const float*)d_in[2];
    const float* W_i   = (const float*)d_in[3];
    const float* b_i   = (const float*)d_in[4];
    const float* W_f   = (const float*)d_in[5];
    const float* b_f   = (const float*)d_in[6];
    const float* W_o   = (const float*)d_in[7];
    const float* b_o   = (const float*)d_in[8];
    const float* W_c   = (const float*)d_in[9];
    const float* b_c   = (const float*)d_in[10];

    float* h_out = (float*)d_out;
    float* c_out = h_out + (size_t)M_DIM * H_DIM;

    const size_t need = (size_t)M_DIM * K_DIM * 2 + (size_t)4 * H_DIM * K_DIM * 2; // 96 MB
    if (ws_size >= need) {
        unsigned short* xh_bf = (unsigned short*)d_ws;
        unsigned short* w_bf  = xh_bf + (size_t)M_DIM * K_DIM;
        int total_threads = (M_DIM * K_DIM + 4 * H_DIM * K_DIM) / 8;  // 6,291,456
        convert_all<<<total_threads / 256, 256, 0, stream>>>(
            x_t, h_t_1, W_i, W_f, W_o, W_c, (u16x8*)xh_bf, (u16x8*)w_bf);
        dim3 grid((H_DIM / BH2) * (M_DIM / BM2));   // 32 * 16 = 512, XCD-swizzled
        lstm_gemm_pipe<<<grid, NT2, 0, stream>>>(
            xh_bf, w_bf, b_i, b_f, b_o, b_c, c_t_1, h_out, c_out);
    } else {
        dim3 grid((H_DIM / BH) * (M_DIM / BM));     // 1024
        lstm_gemm_fb<<<grid, NTHREADS, 0, stream>>>(
            x_t, h_t_1, W_i, W_f, W_o, W_c,
            b_i, b_f, b_o, b_c, c_t_1, h_out, c_out);
    }
}